// Round 9
// baseline (205.212 us; speedup 1.0000x reference)
//
#include <hip/hip_runtime.h>
#include <math.h>

#define DD 64
#define CC 128
#define HH 512
#define BATCH 4096

typedef _Float16 f16;
typedef __attribute__((ext_vector_type(2))) float f32x2;

__device__ __forceinline__ f32x2 splat2(float x) { f32x2 v; v[0] = x; v[1] = x; return v; }

// prep: W2 (512x512) and W1 ctx rows (64..191) -> fp16 in d_ws
__global__ void to_f16(const float* __restrict__ W1, const float* __restrict__ W2,
                       f16* __restrict__ w2h, f16* __restrict__ w1ch) {
    int idx = blockIdx.x * 256 + threadIdx.x;
    if (idx < HH * HH) w2h[idx] = (f16)W2[idx];
    else               w1ch[idx - HH * HH] = (f16)W1[DD * HH + (idx - HH * HH)];
}

__device__ __forceinline__ float fast_softplus(float x) {
    float t = exp2f(-fabsf(x) * 1.44269504f);
    return fmaxf(x, 0.f) + 0.69314718f * log2f(1.f + t);
}

__device__ __forceinline__ float bcast(float x, int l) {
    return __int_as_float(__builtin_amdgcn_readlane(__float_as_int(x), l));
}

typedef const __attribute__((address_space(1))) void* as1_cptr;
typedef __attribute__((address_space(3))) void* as3_ptr;
__device__ __forceinline__ void glds16(const void* g, void* l) {
    __builtin_amdgcn_global_load_lds((as1_cptr)g, (as3_ptr)l, 16, 0, 0);
}
__device__ __forceinline__ void glds4(const void* g, void* l) {
    __builtin_amdgcn_global_load_lds((as1_cptr)g, (as3_ptr)l, 4, 0, 0);
}

union H8 { float4 f4; f16 h[8]; };

// Block = 4 waves x R=2 = 8 batch rows; grid 512 -> 2 blocks/CU, 8 waves/CU
// (the best-measured topology, R6). Lane l owns hidden units 8l..8l+7,
// deg=(j%63)+1. ALL per-step weight data staged in LDS (double-buffered,
// glds): 9 fp16 W2 rows (1KB each: one glds16, one conflict-free b128 read),
// f32 W1[i] row (split-half), 9 f32 W3 rows (128 floats each, 2 glds4).
// Per-CU L2 traffic ~31 KB/step (R6: 77, R8: 121) — attacks the measured
// L2-broadcast bound. Straight-line code, t=8 handled by zeroed multiplier.
// Incremental output acc (R6 scheme): lane c carries {mean col c, prescale
// col 64+c}; z_i is one readlane at step i.

// float-unit offsets inside one buffer
#define SLOT_W1 2304             // after 9*512 halfs (=2304 floats) of W2
#define SLOT_W3 (SLOT_W1 + 512)  // 9 rows x 128 floats
#define BUF_F   (SLOT_W3 + 1152) // 3968 floats = 15872 B per buffer

__global__ __launch_bounds__(256, 2) void made_sample(
    const float* __restrict__ ctx,   // (B, C)
    const float* __restrict__ eps,   // (B, D)
    const float* __restrict__ W1,    // (D+C, H) f32 (feedback rows 0..63)
    const float* __restrict__ b1,    // (H)
    const float* __restrict__ b2,    // (H)
    const float* __restrict__ W3,    // (H, 2D) f32
    const float* __restrict__ b3,    // (2D)
    const f16*   __restrict__ w2h,   // (H, H) fp16
    const f16*   __restrict__ w1ch,  // (C, H) fp16 (W1 rows 64..191)
    float* __restrict__ out)         // (B, D)
{
    const int lane  = threadIdx.x & 63;
    const int w     = threadIdx.x >> 6;          // wave 0..3
    const int rbase = blockIdx.x * 8 + w * 2;    // 2 batch rows per wave
    const int jbase = 8 * lane;

    __shared__ float sbuf[2][BUF_F];             // 2 x 15.5 KB

    int deg[8];
    #pragma unroll
    for (int u = 0; u < 8; ++u) deg[u] = (jbase + u) % 63 + 1;

    float p1[2][8];
    f32x2 p2[2][4], acc[2];
    #pragma unroll
    for (int u = 0; u < 8; ++u) {
        float t1 = b1[jbase + u];
        p1[0][u] = t1; p1[1][u] = t1;
    }
    #pragma unroll
    for (int j = 0; j < 4; ++j) {
        f32x2 t2; t2[0] = b2[jbase + 2 * j]; t2[1] = b2[jbase + 2 * j + 1];
        p2[0][j] = t2; p2[1][j] = t2;
    }
    acc[0] = splat2(0.f);
    acc[1] = splat2(0.f);

    float ca[2], cb[2], ep[2];
    #pragma unroll
    for (int r = 0; r < 2; ++r) {
        ca[r] = ctx[(rbase + r) * CC + lane];
        cb[r] = ctx[(rbase + r) * CC + 64 + lane];
        ep[r] = eps[(rbase + r) * DD + lane];
    }
    const float b3m = b3[lane];
    const float b3p = b3[64 + lane];

    f16* bufh = (f16*)&sbuf[0][0];               // half-typed view (buffer 0)
    const int bufh_stride = BUF_F * 2;           // halfs per buffer

    // ctx chunk ch: fp16 rows 8ch..8ch+7 -> W2 area slots 0..7 (8 glds16 / 4 waves)
    auto stage_ctx = [&](int ch, int bsel) {
        f16* bh = bufh + bsel * bufh_stride;
        #pragma unroll
        for (int o = 0; o < 2; ++o) {
            const int q = 4 * o + w;             // 0..7
            glds16(w1ch + (8 * ch + q) * HH + lane * 8, bh + q * 512);
        }
    };
    // step `in`: 29 staging ops round-robin over 4 waves.
    auto stage_step = [&](int in, int bsel) {
        const int basen = (in == 0) ? 0 : (in - 1);
        f16*   bh = bufh + bsel * bufh_stride;
        float* bf = &sbuf[bsel][0];
        #pragma unroll
        for (int o8 = 0; o8 < 8; ++o8) {
            const int o = 4 * o8 + w;            // 0..31, take o<29
            if (o < 9) {                         // fp16 W2 row t=o
                int k = basen + 63 * o;
                if (k >= HH) k = HH - 1;         // mult zeroed in compute
                glds16(w2h + k * HH + lane * 8, bh + o * 512);
            } else if (o < 11) {                 // f32 W1 row, split-half
                const int hf = o - 9;
                glds16(W1 + in * HH + lane * 8 + hf * 4, bf + SLOT_W1 + hf * 256);
            } else if (o < 29) {                 // f32 W3 rows, 2 glds4 each
                const int t = (o - 11) >> 1, hf = (o - 11) & 1;
                int k = basen + 63 * t;
                if (k >= HH) k = HH - 1;
                glds4(W3 + k * (2 * DD) + hf * 64 + lane,
                      bf + SLOT_W3 + t * 128 + hf * 64);
            }
        }
    };

    // ---- context init: pre1 += ctx @ W1[D:,:], 16 chunks of 8 fp16 rows ----
    stage_ctx(0, 0);
    __syncthreads();
    #pragma unroll 1
    for (int ch = 0; ch < 16; ++ch) {
        const int cs = ch & 1;
        if (ch < 15) stage_ctx(ch + 1, cs ^ 1);
        else         stage_step(0, 0);           // 16&1==0: step-0 parity OK
        f16* bh = bufh + cs * bufh_stride;
        #pragma unroll
        for (int q = 0; q < 8; ++q) {
            H8 uw; uw.f4 = *(const float4*)(bh + q * 512 + lane * 8);
            const int c = 8 * ch + q;
            #pragma unroll
            for (int r = 0; r < 2; ++r) {
                const float cv = bcast((ch < 8) ? ca[r] : cb[r], c & 63);
                #pragma unroll
                for (int u = 0; u < 8; ++u)
                    p1[r][u] = fmaf((float)uw.h[u], cv, p1[r][u]);
            }
        }
        __syncthreads();
    }

    float z[2] = {0.f, 0.f};

    // ---- autoregressive main loop ----
    #pragma unroll 1
    for (int i = 0; i < DD; ++i) {
        const int cs = i & 1;
        if (i < 63) stage_step(i + 1, cs ^ 1);

        f16*   bh = bufh + cs * bufh_stride;
        float* bf = &sbuf[cs][0];
        const int base = (i == 0) ? 0 : (i - 1);
        const float vm8 = (base + 504 < HH) ? 1.f : 0.f;   // t=8 validity (i<=8)

        // batched LDS preloads off the serial chain
        f32x2 w1v[4];
        {
            float4 a = *(const float4*)(bf + SLOT_W1 + lane * 4);
            float4 b = *(const float4*)(bf + SLOT_W1 + 256 + lane * 4);
            w1v[0][0] = a.x; w1v[0][1] = a.y; w1v[1][0] = a.z; w1v[1][1] = a.w;
            w1v[2][0] = b.x; w1v[2][1] = b.y; w1v[3][0] = b.z; w1v[3][1] = b.w;
        }
        f32x2 w3v[9];
        #pragma unroll
        for (int t = 0; t < 9; ++t) {
            w3v[t][0] = bf[SLOT_W3 + t * 128 + lane];
            w3v[t][1] = bf[SLOT_W3 + t * 128 + 64 + lane];
        }

        // (a) finalized h1 (deg==i); zero at i==0
        float m[2];
        #pragma unroll
        for (int r = 0; r < 2; ++r) {
            float mv = 0.f;
            #pragma unroll
            for (int u = 0; u < 8; ++u) mv = (deg[u] == i) ? p1[r][u] : mv;
            m[r] = fmaxf(mv, 0.f);
        }

        // (b) rank-9 update of pre2 from fp16 W2 rows (fma_mix)
        #pragma unroll
        for (int t = 0; t < 9; ++t) {
            const int k = base + 63 * t;
            H8 uw; uw.f4 = *(const float4*)(bh + t * 512 + lane * 8);
            float h0, h1v;
            if (t == 8) {                        // lane 63 for k in [504,512)
                h0  = vm8 * bcast(m[0], 63);
                h1v = vm8 * bcast(m[1], 63);
            } else {
                h0  = bcast(m[0], k >> 3);
                h1v = bcast(m[1], k >> 3);
            }
            #pragma unroll
            for (int u = 0; u < 8; ++u) {
                const float wu = (float)uw.h[u];
                p2[0][u >> 1][u & 1] = fmaf(wu, h0,  p2[0][u >> 1][u & 1]);
                p2[1][u >> 1][u & 1] = fmaf(wu, h1v, p2[1][u >> 1][u & 1]);
            }
        }

        // (c) newly-final h2 (deg==i)
        float hn[2];
        #pragma unroll
        for (int r = 0; r < 2; ++r) {
            float hv = 0.f;
            #pragma unroll
            for (int u = 0; u < 8; ++u)
                hv = (deg[u] == i) ? p2[r][u >> 1][u & 1] : hv;
            hn[r] = fmaxf(hv, 0.f);
        }

        // (d) incremental output acc from staged W3 rows
        #pragma unroll
        for (int t = 0; t < 8; ++t) {
            const int k = base + 63 * t;
            acc[0] += splat2(bcast(hn[0], k >> 3)) * w3v[t];
            acc[1] += splat2(bcast(hn[1], k >> 3)) * w3v[t];
        }
        acc[0] += splat2(vm8 * bcast(hn[0], 63)) * w3v[8];
        acc[1] += splat2(vm8 * bcast(hn[1], 63)) * w3v[8];

        // (e) z_i: column i's totals live in lane i
        #pragma unroll
        for (int r = 0; r < 2; ++r) {
            const float am = acc[r][0] + b3m;
            const float ap = acc[r][1] + b3p;
            const float sp = fast_softplus(ap);
            const float zc = fmaf(sp, ep[r], am);
            const float zi = bcast(zc, i);
            if (lane == i) z[r] = zi;
            const f32x2 zi2 = splat2(zi);
            #pragma unroll
            for (int j = 0; j < 4; ++j) {
                f32x2 t = p1[r][2 * j] < 0.f ? splat2(0.f) : splat2(0.f); (void)t;
            }
            #pragma unroll
            for (int u = 0; u < 8; ++u)
                p1[r][u] = fmaf(zi, w1v[u >> 1][u & 1], p1[r][u]);
            (void)zi2;
        }

        __syncthreads();
    }

    #pragma unroll
    for (int r = 0; r < 2; ++r) out[(rbase + r) * DD + lane] = z[r];
}

extern "C" void kernel_launch(void* const* d_in, const int* in_sizes, int n_in,
                              void* d_out, int out_size, void* d_ws, size_t ws_size,
                              hipStream_t stream) {
    const float* ctx = (const float*)d_in[0];
    const float* eps = (const float*)d_in[1];
    const float* W1  = (const float*)d_in[2];
    const float* b1  = (const float*)d_in[3];
    const float* W2  = (const float*)d_in[4];
    const float* b2  = (const float*)d_in[5];
    const float* W3  = (const float*)d_in[6];
    const float* b3  = (const float*)d_in[7];

    f16* w2h  = (f16*)d_ws;                    // 512*512 halfs
    f16* w1ch = w2h + HH * HH;                 // 128*512 halfs

    to_f16<<<(HH * HH + CC * HH) / 256, 256, 0, stream>>>(W1, W2, w2h, w1ch);
    made_sample<<<BATCH / 8, 256, 0, stream>>>(ctx, eps, W1, b1, b2, W3, b3,
                                               w2h, w1ch, (float*)d_out);
}